// Round 1
// baseline (1341.432 us; speedup 1.0000x reference)
//
#include <hip/hip_runtime.h>
#include <math.h>

// Problem constants: B=2, S=2048, E=1024, NH=16, hd=64, T=1 (seq = S)
#define BB 2
#define SS 2048
#define EE 1024
#define NHH 16
#define HD 64
#define HD2 32

// ---------------- kernel 1: RoPE cos/sin tables ----------------
__global__ __launch_bounds__(256) void rope_table_k(float* __restrict__ ct,
                                                    float* __restrict__ st) {
    int idx = blockIdx.x * 256 + threadIdx.x;   // idx = s*32 + p
    if (idx >= SS * HD2) return;
    int s = idx >> 5, p = idx & 31;
    double inv = pow(10000.0, -(double)(2 * p) / 64.0);
    double ang = (double)s * inv;
    ct[idx] = (float)cos(ang);
    st[idx] = (float)sin(ang);
}

// ---------------- kernel 2: QKV GEMM + bias + fused RoPE ----------------
// X: (B*S, E) row-major; W: (3E, E) row-major; computes X @ W^T + bias,
// applies RoPE to q,k sections, writes qkv ws as [3][B*NH][S][64].
__global__ __launch_bounds__(256) void qkv_rope_k(
    const float* __restrict__ X, const float* __restrict__ W,
    const float* __restrict__ bias,
    const float* __restrict__ ct, const float* __restrict__ st,
    float* __restrict__ qkv)
{
    __shared__ float As[64][17];   // [m-local][kk], stride 17 -> <=2-way conflicts
    __shared__ float Ws[64][17];   // [n-local][kk]

    const int tid = threadIdx.x;
    const int tx = tid & 15, ty = tid >> 4;
    const int m0 = blockIdx.y * 64;
    const int n0blk = blockIdx.x * 64;

    const int lrow = tid >> 2;
    const int lseg = (tid & 3) * 4;

    float acc[4][4];
#pragma unroll
    for (int i = 0; i < 4; i++)
#pragma unroll
        for (int j = 0; j < 4; j++) acc[i][j] = 0.f;

    for (int k0 = 0; k0 < EE; k0 += 16) {
        float4 av = *(const float4*)(X + (size_t)(m0 + lrow) * EE + k0 + lseg);
        float4 wv = *(const float4*)(W + (size_t)(n0blk + lrow) * EE + k0 + lseg);
        __syncthreads();   // previous iteration's reads done
        As[lrow][lseg + 0] = av.x; As[lrow][lseg + 1] = av.y;
        As[lrow][lseg + 2] = av.z; As[lrow][lseg + 3] = av.w;
        Ws[lrow][lseg + 0] = wv.x; Ws[lrow][lseg + 1] = wv.y;
        Ws[lrow][lseg + 2] = wv.z; Ws[lrow][lseg + 3] = wv.w;
        __syncthreads();
#pragma unroll
        for (int kk = 0; kk < 16; kk++) {
            float a0 = As[ty * 4 + 0][kk];
            float a1 = As[ty * 4 + 1][kk];
            float a2 = As[ty * 4 + 2][kk];
            float a3 = As[ty * 4 + 3][kk];
            float b0 = Ws[tx * 4 + 0][kk];
            float b1 = Ws[tx * 4 + 1][kk];
            float b2 = Ws[tx * 4 + 2][kk];
            float b3 = Ws[tx * 4 + 3][kk];
            acc[0][0] += a0 * b0; acc[0][1] += a0 * b1; acc[0][2] += a0 * b2; acc[0][3] += a0 * b3;
            acc[1][0] += a1 * b0; acc[1][1] += a1 * b1; acc[1][2] += a1 * b2; acc[1][3] += a1 * b3;
            acc[2][0] += a2 * b0; acc[2][1] += a2 * b1; acc[2][2] += a2 * b2; acc[2][3] += a2 * b3;
            acc[3][0] += a3 * b0; acc[3][1] += a3 * b1; acc[3][2] += a3 * b2; acc[3][3] += a3 * b3;
        }
    }

    // epilogue: bias + RoPE + scatter into [3][B*NH][S][64]
    const int n0 = n0blk + tx * 4;           // 4 consecutive cols, same section+head
    const int sec = n0 >> 10;                // 0=q,1=k,2=v
    const int e0 = n0 & 1023;
    const int h = e0 >> 6;
    const int d0 = e0 & 63;                  // multiple of 4 -> pairs aligned
    const float bs0 = bias[n0], bs1 = bias[n0 + 1], bs2 = bias[n0 + 2], bs3 = bias[n0 + 3];

#pragma unroll
    for (int i = 0; i < 4; i++) {
        int m = m0 + ty * 4 + i;
        int b = m >> 11;          // m / 2048
        int srow = m & 2047;
        float x0 = acc[i][0] + bs0;
        float x1 = acc[i][1] + bs1;
        float x2 = acc[i][2] + bs2;
        float x3 = acc[i][3] + bs3;
        float4 o;
        if (sec < 2) {
            int p0 = d0 >> 1;
            float c0 = ct[srow * 32 + p0],     s0 = st[srow * 32 + p0];
            float c1 = ct[srow * 32 + p0 + 1], s1 = st[srow * 32 + p0 + 1];
            o.x = x0 * c0 - x1 * s0;   // even
            o.y = x0 * s0 + x1 * c0;   // odd
            o.z = x2 * c1 - x3 * s1;
            o.w = x2 * s1 + x3 * c1;
        } else {
            o = make_float4(x0, x1, x2, x3);
        }
        size_t dst = ((size_t)(sec * (BB * NHH) + b * NHH + h) * SS + srow) * HD + d0;
        *(float4*)(qkv + dst) = o;
    }
}

// ---------------- kernel 3: flash attention (fp32, online softmax) --------
// qkv layout [3][B*NH][S][64]. One block = (b,h) x 32-query tile.
__global__ __launch_bounds__(256) void attn_k(const float* __restrict__ qkv,
                                              float* __restrict__ out)
{
    __shared__ float Qs[32][68];   // stride 68 keeps b128 reads conflict-free
    __shared__ float Ks[32][68];
    __shared__ float Vs[32][68];
    __shared__ float Ps[32][36];

    const int tid = threadIdx.x;
    const int row = tid >> 3;      // query row in tile (0..31)
    const int l8 = tid & 7;        // lane-in-row (0..7)
    const int bh = blockIdx.y;     // b*NH + h
    const int q0 = blockIdx.x * 32;

    const float* qb = qkv + ((size_t)bh * SS + q0) * HD;
    const float* kb = qkv + (size_t)(BB * NHH + bh) * SS * HD;
    const float* vb = qkv + (size_t)(2 * BB * NHH + bh) * SS * HD;

    // stage Q tile (pre-scaled by 1/sqrt(64))
#pragma unroll
    for (int i = 0; i < 2; i++) {
        int idx = tid + i * 256;
        int r = idx >> 4, c4 = (idx & 15) * 4;
        float4 v = *(const float4*)(qb + r * HD + c4);
        v.x *= 0.125f; v.y *= 0.125f; v.z *= 0.125f; v.w *= 0.125f;
        *(float4*)&Qs[r][c4] = v;
    }

    float m_r = -INFINITY, l_r = 0.f;
    float acc[8];
#pragma unroll
    for (int i = 0; i < 8; i++) acc[i] = 0.f;
    const int d0 = l8 * 8;

    for (int kt = 0; kt < SS / 32; kt++) {
        __syncthreads();   // prev-iter reads done (also covers initial Q staging)
#pragma unroll
        for (int i = 0; i < 2; i++) {
            int idx = tid + i * 256;
            int r = idx >> 4, c4 = (idx & 15) * 4;
            float4 kv4 = *(const float4*)(kb + (size_t)(kt * 32 + r) * HD + c4);
            float4 vv4 = *(const float4*)(vb + (size_t)(kt * 32 + r) * HD + c4);
            *(float4*)&Ks[r][c4] = kv4;
            *(float4*)&Vs[r][c4] = vv4;
        }
        __syncthreads();

        // QK^T: this thread -> keys j = l8 + 8*jj (strided -> conflict-free reads)
        float sc[4] = {0.f, 0.f, 0.f, 0.f};
#pragma unroll
        for (int kk = 0; kk < HD; kk += 4) {
            float4 qv = *(const float4*)&Qs[row][kk];
#pragma unroll
            for (int jj = 0; jj < 4; jj++) {
                float4 kv = *(const float4*)&Ks[l8 + 8 * jj][kk];
                sc[jj] += qv.x * kv.x + qv.y * kv.y + qv.z * kv.z + qv.w * kv.w;
            }
        }

        // online softmax across the row's 8 lanes
        float mt = fmaxf(fmaxf(sc[0], sc[1]), fmaxf(sc[2], sc[3]));
        mt = fmaxf(mt, __shfl_xor(mt, 1));
        mt = fmaxf(mt, __shfl_xor(mt, 2));
        mt = fmaxf(mt, __shfl_xor(mt, 4));
        float mn = fmaxf(m_r, mt);
        float ps = 0.f;
#pragma unroll
        for (int jj = 0; jj < 4; jj++) {
            float p = __expf(sc[jj] - mn);
            Ps[row][l8 + 8 * jj] = p;
            ps += p;
        }
        ps += __shfl_xor(ps, 1);
        ps += __shfl_xor(ps, 2);
        ps += __shfl_xor(ps, 4);
        float alpha = __expf(m_r - mn);
        l_r = l_r * alpha + ps;
        m_r = mn;
#pragma unroll
        for (int i = 0; i < 8; i++) acc[i] *= alpha;
        __syncthreads();   // P visible

        // P @ V: this thread owns dims [d0, d0+8) of its row
#pragma unroll
        for (int j = 0; j < 32; j++) {
            float p = Ps[row][j];
            float4 v0 = *(const float4*)&Vs[j][d0];
            float4 v1 = *(const float4*)&Vs[j][d0 + 4];
            acc[0] += p * v0.x; acc[1] += p * v0.y; acc[2] += p * v0.z; acc[3] += p * v0.w;
            acc[4] += p * v1.x; acc[5] += p * v1.y; acc[6] += p * v1.z; acc[7] += p * v1.w;
        }
    }

    float inv_l = 1.f / l_r;
    int b = bh >> 4, h = bh & 15;
    size_t dst = ((size_t)(b * SS + q0 + row)) * EE + h * HD + d0;
    float4 o0 = make_float4(acc[0] * inv_l, acc[1] * inv_l, acc[2] * inv_l, acc[3] * inv_l);
    float4 o1 = make_float4(acc[4] * inv_l, acc[5] * inv_l, acc[6] * inv_l, acc[7] * inv_l);
    *(float4*)(out + dst) = o0;
    *(float4*)(out + dst + 4) = o1;
}

extern "C" void kernel_launch(void* const* d_in, const int* in_sizes, int n_in,
                              void* d_out, int out_size, void* d_ws, size_t ws_size,
                              hipStream_t stream) {
    const float* X    = (const float*)d_in[0];   // hidden_states (B,S,E)
    const float* W    = (const float*)d_in[1];   // in_proj_weight (3E,E)
    const float* bias = (const float*)d_in[2];   // in_proj_bias (3E)
    float* out = (float*)d_out;

    float* ws  = (float*)d_ws;
    float* ct  = ws;                      // S*32 floats
    float* st  = ws + SS * HD2;           // S*32 floats
    float* qkv = ws + 2 * SS * HD2;       // 3*B*NH*S*64 floats = 48 MB

    rope_table_k<<<(SS * HD2 + 255) / 256, 256, 0, stream>>>(ct, st);
    qkv_rope_k<<<dim3(3 * EE / 64, BB * SS / 64), 256, 0, stream>>>(X, W, bias, ct, st, qkv);
    attn_k<<<dim3(SS / 32, BB * NHH), 256, 0, stream>>>(qkv, out);
}

// Round 2
// 735.403 us; speedup vs baseline: 1.8241x; 1.8241x over previous
//
#include <hip/hip_runtime.h>
#include <math.h>

// Problem constants: B=2, S=2048, E=1024, NH=16, hd=64, T=1 (seq = S)
#define BB 2
#define SS 2048
#define EE 1024
#define NHH 16
#define HD 64
#define HD2 32

typedef __attribute__((ext_vector_type(8))) short bf16x8;   // 8 bf16 = 4 VGPRs
typedef __attribute__((ext_vector_type(4))) float f32x4;    // MFMA accumulator

static __device__ __forceinline__ unsigned short f2bf(float x) {
    union { float f; unsigned u; } v; v.f = x;
    unsigned r = v.u + 0x7fffu + ((v.u >> 16) & 1u);   // round-to-nearest-even
    return (unsigned short)(r >> 16);
}
static __device__ __forceinline__ float bf2f(unsigned short h) {
    union { unsigned u; float f; } v; v.u = ((unsigned)h) << 16;
    return v.f;
}

// ---------------- kernel 1: RoPE cos/sin tables ----------------
__global__ __launch_bounds__(256) void rope_table_k(float* __restrict__ ct,
                                                    float* __restrict__ st) {
    int idx = blockIdx.x * 256 + threadIdx.x;   // idx = s*32 + p
    if (idx >= SS * HD2) return;
    int s = idx >> 5, p = idx & 31;
    double inv = pow(10000.0, -(double)(2 * p) / 64.0);
    double ang = (double)s * inv;
    ct[idx] = (float)cos(ang);
    st[idx] = (float)sin(ang);
}

// ---------------- kernel 2: QKV GEMM + bias + fused RoPE + hi/lo split ----
// Writes Q,K in the QK-fragment swizzle, V in the PV(B-operand) swizzle.
// Q/K swizzle per bh (131072 bf16): [s16(128)][kc(2)][quad(4)][l15=s&15][j=d&7]
// V  swizzle per bh:                [s32(64)][dc(4)][quad=(s>>3)&3][l15=d&15][j=s&7]
__global__ __launch_bounds__(256) void qkv_rope_k(
    const float* __restrict__ X, const float* __restrict__ W,
    const float* __restrict__ bias,
    const float* __restrict__ ct, const float* __restrict__ st,
    unsigned short* __restrict__ Qh, unsigned short* __restrict__ Ql,
    unsigned short* __restrict__ Kh, unsigned short* __restrict__ Kl,
    unsigned short* __restrict__ Vh, unsigned short* __restrict__ Vl)
{
    __shared__ float As[64][17];
    __shared__ float Ws[64][17];

    const int tid = threadIdx.x;
    const int tx = tid & 15, ty = tid >> 4;
    const int m0 = blockIdx.y * 64;
    const int n0blk = blockIdx.x * 64;

    const int lrow = tid >> 2;
    const int lseg = (tid & 3) * 4;

    float acc[4][4];
#pragma unroll
    for (int i = 0; i < 4; i++)
#pragma unroll
        for (int j = 0; j < 4; j++) acc[i][j] = 0.f;

    for (int k0 = 0; k0 < EE; k0 += 16) {
        float4 av = *(const float4*)(X + (size_t)(m0 + lrow) * EE + k0 + lseg);
        float4 wv = *(const float4*)(W + (size_t)(n0blk + lrow) * EE + k0 + lseg);
        __syncthreads();
        As[lrow][lseg + 0] = av.x; As[lrow][lseg + 1] = av.y;
        As[lrow][lseg + 2] = av.z; As[lrow][lseg + 3] = av.w;
        Ws[lrow][lseg + 0] = wv.x; Ws[lrow][lseg + 1] = wv.y;
        Ws[lrow][lseg + 2] = wv.z; Ws[lrow][lseg + 3] = wv.w;
        __syncthreads();
#pragma unroll
        for (int kk = 0; kk < 16; kk++) {
            float a0 = As[ty * 4 + 0][kk];
            float a1 = As[ty * 4 + 1][kk];
            float a2 = As[ty * 4 + 2][kk];
            float a3 = As[ty * 4 + 3][kk];
            float b0 = Ws[tx * 4 + 0][kk];
            float b1 = Ws[tx * 4 + 1][kk];
            float b2 = Ws[tx * 4 + 2][kk];
            float b3 = Ws[tx * 4 + 3][kk];
            acc[0][0] += a0 * b0; acc[0][1] += a0 * b1; acc[0][2] += a0 * b2; acc[0][3] += a0 * b3;
            acc[1][0] += a1 * b0; acc[1][1] += a1 * b1; acc[1][2] += a1 * b2; acc[1][3] += a1 * b3;
            acc[2][0] += a2 * b0; acc[2][1] += a2 * b1; acc[2][2] += a2 * b2; acc[2][3] += a2 * b3;
            acc[3][0] += a3 * b0; acc[3][1] += a3 * b1; acc[3][2] += a3 * b2; acc[3][3] += a3 * b3;
        }
    }

    const int n0 = n0blk + tx * 4;
    const int sec = n0 >> 10;                // 0=q,1=k,2=v
    const int e0 = n0 & 1023;
    const int h = e0 >> 6;
    const int d0 = e0 & 63;                  // multiple of 4
    const float bs0 = bias[n0], bs1 = bias[n0 + 1], bs2 = bias[n0 + 2], bs3 = bias[n0 + 3];

    const int m_base = m0 + ty * 4;
    const int bidx = m_base >> 11;           // all 4 rows in same batch (m0 mult of 64)
    const int bh = bidx * NHH + h;
    const size_t abase = (size_t)bh * 131072;

    if (sec == 2) {
        // V: contiguity is along s (i-loop), one 8B store per dim per array
        float vals[4][4];
#pragma unroll
        for (int i = 0; i < 4; i++) {
            vals[i][0] = acc[i][0] + bs0; vals[i][1] = acc[i][1] + bs1;
            vals[i][2] = acc[i][2] + bs2; vals[i][3] = acc[i][3] + bs3;
        }
        const int s0 = m_base & 2047;        // multiple of 4
#pragma unroll
        for (int jj = 0; jj < 4; jj++) {
            int dj = d0 + jj;
            unsigned short hv[4], lv[4];
#pragma unroll
            for (int i = 0; i < 4; i++) {
                float x = vals[i][jj];
                hv[i] = f2bf(x);
                lv[i] = f2bf(x - bf2f(hv[i]));
            }
            size_t off = abase +
                ((((size_t)(s0 >> 5) * 4 + (dj >> 4)) * 4 + ((s0 >> 3) & 3)) * 16 + (dj & 15)) * 8 + (s0 & 7);
            *(ushort4*)(Vh + off) = make_ushort4(hv[0], hv[1], hv[2], hv[3]);
            *(ushort4*)(Vl + off) = make_ushort4(lv[0], lv[1], lv[2], lv[3]);
        }
    } else {
        unsigned short* Ahi = (sec == 0) ? Qh : Kh;
        unsigned short* Alo = (sec == 0) ? Ql : Kl;
        const float sc = (sec == 0) ? 0.125f : 1.0f;   // fold 1/sqrt(hd) into Q
        const int p0 = d0 >> 1;
#pragma unroll
        for (int i = 0; i < 4; i++) {
            int srow = (m_base + i) & 2047;
            float x0 = acc[i][0] + bs0;
            float x1 = acc[i][1] + bs1;
            float x2 = acc[i][2] + bs2;
            float x3 = acc[i][3] + bs3;
            float c0 = ct[srow * 32 + p0],     s0v = st[srow * 32 + p0];
            float c1 = ct[srow * 32 + p0 + 1], s1v = st[srow * 32 + p0 + 1];
            float o0 = (x0 * c0 - x1 * s0v) * sc;
            float o1 = (x0 * s0v + x1 * c0) * sc;
            float o2 = (x2 * c1 - x3 * s1v) * sc;
            float o3 = (x2 * s1v + x3 * c1) * sc;
            unsigned short h0 = f2bf(o0), h1 = f2bf(o1), h2 = f2bf(o2), h3 = f2bf(o3);
            unsigned short l0 = f2bf(o0 - bf2f(h0)), l1 = f2bf(o1 - bf2f(h1));
            unsigned short l2 = f2bf(o2 - bf2f(h2)), l3 = f2bf(o3 - bf2f(h3));
            size_t off = abase +
                ((((size_t)(srow >> 4) * 2 + (d0 >> 5)) * 4 + ((d0 >> 3) & 3)) * 16 + (srow & 15)) * 8 + (d0 & 7);
            *(ushort4*)(Ahi + off) = make_ushort4(h0, h1, h2, h3);
            *(ushort4*)(Alo + off) = make_ushort4(l0, l1, l2, l3);
        }
    }
}

// ---------------- kernel 3: flash attention, split-bf16 MFMA --------------
// wg = 256 threads = 4 waves; wave owns 32 q rows; 64-key tiles.
// Scores computed transposed (A=K, B=Q^T) so softmax state is per-lane (q=lane&15).
__global__ __launch_bounds__(256, 2) void attn_mfma_k(
    const unsigned short* __restrict__ Qh, const unsigned short* __restrict__ Ql,
    const unsigned short* __restrict__ Khg, const unsigned short* __restrict__ Klg,
    const unsigned short* __restrict__ Vhg, const unsigned short* __restrict__ Vlg,
    float* __restrict__ out)
{
    __shared__ __align__(16) unsigned short Kh[4096];
    __shared__ __align__(16) unsigned short Kl[4096];
    __shared__ __align__(16) unsigned short Vh[4096];
    __shared__ __align__(16) unsigned short Vl[4096];
    __shared__ __align__(16) unsigned short Pbuf[4][2176];  // per wave: hi [0,1088), lo [1088,2176); block stride 136

    const int tid  = threadIdx.x;
    const int wave = tid >> 6;
    const int lane = tid & 63;
    const int quad = lane >> 4;
    const int l15  = lane & 15;
    const int bh   = blockIdx.y;
    const int b    = bh >> 4, h = bh & 15;
    const int q_wave = blockIdx.x * 128 + wave * 32;
    const size_t abase = (size_t)bh * 131072;

    // Q B-fragments (persistent): [nc][kc][hi/lo]
    bf16x8 qf[2][2][2];
#pragma unroll
    for (int nc = 0; nc < 2; nc++)
#pragma unroll
        for (int kc = 0; kc < 2; kc++) {
            size_t off = abase + ((((size_t)((q_wave >> 4) + nc) * 2 + kc) * 4 + quad) * 16 + l15) * 8;
            qf[nc][kc][0] = *(const bf16x8*)(Qh + off);
            qf[nc][kc][1] = *(const bf16x8*)(Ql + off);
        }

    f32x4 acc[2][4];
#pragma unroll
    for (int nc = 0; nc < 2; nc++)
#pragma unroll
        for (int dc = 0; dc < 4; dc++) acc[nc][dc] = (f32x4){0.f, 0.f, 0.f, 0.f};
    float mst[2] = {-INFINITY, -INFINITY};
    float lst[2] = {0.f, 0.f};

    for (int kt = 0; kt < SS / 64; kt++) {
        __syncthreads();   // previous tile's LDS reads done
        {
            const unsigned short* gsrc0 = Khg + abase + (size_t)kt * 4096;
            const unsigned short* gsrc1 = Klg + abase + (size_t)kt * 4096;
            const unsigned short* gsrc2 = Vhg + abase + (size_t)kt * 4096;
            const unsigned short* gsrc3 = Vlg + abase + (size_t)kt * 4096;
            float4 t0 = *(const float4*)(gsrc0 + (size_t)tid * 8);
            float4 t1 = *(const float4*)(gsrc0 + (size_t)(tid + 256) * 8);
            float4 t2 = *(const float4*)(gsrc1 + (size_t)tid * 8);
            float4 t3 = *(const float4*)(gsrc1 + (size_t)(tid + 256) * 8);
            float4 t4 = *(const float4*)(gsrc2 + (size_t)tid * 8);
            float4 t5 = *(const float4*)(gsrc2 + (size_t)(tid + 256) * 8);
            float4 t6 = *(const float4*)(gsrc3 + (size_t)tid * 8);
            float4 t7 = *(const float4*)(gsrc3 + (size_t)(tid + 256) * 8);
            *(float4*)(Kh + tid * 8)         = t0;
            *(float4*)(Kh + (tid + 256) * 8) = t1;
            *(float4*)(Kl + tid * 8)         = t2;
            *(float4*)(Kl + (tid + 256) * 8) = t3;
            *(float4*)(Vh + tid * 8)         = t4;
            *(float4*)(Vh + (tid + 256) * 8) = t5;
            *(float4*)(Vl + tid * 8)         = t6;
            *(float4*)(Vl + (tid + 256) * 8) = t7;
        }
        __syncthreads();

        // ---- QK^T (transposed: St[key][q]) ----
        f32x4 stt[2][4];   // [nc][mc]
#pragma unroll
        for (int mc = 0; mc < 4; mc++) {
            int boff0 = ((mc * 2 + 0) * 4 + quad) * 128 + l15 * 8;
            int boff1 = ((mc * 2 + 1) * 4 + quad) * 128 + l15 * 8;
            bf16x8 ah0 = *(const bf16x8*)(Kh + boff0);
            bf16x8 ah1 = *(const bf16x8*)(Kh + boff1);
            bf16x8 al0 = *(const bf16x8*)(Kl + boff0);
            bf16x8 al1 = *(const bf16x8*)(Kl + boff1);
#pragma unroll
            for (int nc = 0; nc < 2; nc++) {
                f32x4 s = (f32x4){0.f, 0.f, 0.f, 0.f};
                s = __builtin_amdgcn_mfma_f32_16x16x32_bf16(ah0, qf[nc][0][0], s, 0, 0, 0);
                s = __builtin_amdgcn_mfma_f32_16x16x32_bf16(ah1, qf[nc][1][0], s, 0, 0, 0);
                s = __builtin_amdgcn_mfma_f32_16x16x32_bf16(ah0, qf[nc][0][1], s, 0, 0, 0);
                s = __builtin_amdgcn_mfma_f32_16x16x32_bf16(ah1, qf[nc][1][1], s, 0, 0, 0);
                s = __builtin_amdgcn_mfma_f32_16x16x32_bf16(al0, qf[nc][0][0], s, 0, 0, 0);
                s = __builtin_amdgcn_mfma_f32_16x16x32_bf16(al1, qf[nc][1][0], s, 0, 0, 0);
                stt[nc][mc] = s;
            }
        }

        // ---- V B-fragments (held in regs, reused across nc) ----
        bf16x8 vf[4][2][2];   // [dc][kk2][hi/lo]
#pragma unroll
        for (int dc = 0; dc < 4; dc++)
#pragma unroll
            for (int kk2 = 0; kk2 < 2; kk2++) {
                int off = ((kk2 * 4 + dc) * 4 + quad) * 128 + l15 * 8;
                vf[dc][kk2][0] = *(const bf16x8*)(Vh + off);
                vf[dc][kk2][1] = *(const bf16x8*)(Vl + off);
            }

#pragma unroll
        for (int nc = 0; nc < 2; nc++) {
            // online softmax; this lane owns q = q_wave + nc*16 + l15 (replicated over quads)
            float mt = -INFINITY;
#pragma unroll
            for (int mc = 0; mc < 4; mc++)
#pragma unroll
                for (int r = 0; r < 4; r++) mt = fmaxf(mt, stt[nc][mc][r]);
            mt = fmaxf(mt, __shfl_xor(mt, 16));
            mt = fmaxf(mt, __shfl_xor(mt, 32));
            float mnew = fmaxf(mst[nc], mt);
            float alpha = __expf(mst[nc] - mnew);
            float p[4][4];
            float ps = 0.f;
#pragma unroll
            for (int mc = 0; mc < 4; mc++)
#pragma unroll
                for (int r = 0; r < 4; r++) {
                    float e = __expf(stt[nc][mc][r] - mnew);
                    p[mc][r] = e;
                    ps += e;
                }
            ps += __shfl_xor(ps, 16);
            ps += __shfl_xor(ps, 32);
            lst[nc] = lst[nc] * alpha + ps;
            mst[nc] = mnew;

            // rescale accumulator rows (C-layout row = quad*4 + r)
            float ar[4];
#pragma unroll
            for (int r = 0; r < 4; r++)
                ar[r] = __shfl(alpha, (lane & 48) + ((lane >> 4) << 2) + r);
#pragma unroll
            for (int dc = 0; dc < 4; dc++)
#pragma unroll
                for (int r = 0; r < 4; r++) acc[nc][dc][r] *= ar[r];

            // pack P hi/lo and round-trip through per-wave LDS into A-operand layout
            unsigned short* Pw = Pbuf[wave];
#pragma unroll
            for (int mc = 0; mc < 4; mc++)
#pragma unroll
                for (int pr = 0; pr < 2; pr++) {
                    float p0f = p[mc][2 * pr], p1f = p[mc][2 * pr + 1];
                    unsigned short h0 = f2bf(p0f), h1 = f2bf(p1f);
                    unsigned short lo0 = f2bf(p0f - bf2f(h0));
                    unsigned short lo1 = f2bf(p1f - bf2f(h1));
                    int kk2 = mc >> 1;
                    int quadp = (mc & 1) * 2 + (quad >> 1);
                    int j = (quad & 1) * 4 + 2 * pr;
                    int off = (kk2 * 4 + quadp) * 136 + l15 * 8 + j;
                    *(unsigned int*)(Pw + off)        = (unsigned int)h0 | ((unsigned int)h1 << 16);
                    *(unsigned int*)(Pw + 1088 + off) = (unsigned int)lo0 | ((unsigned int)lo1 << 16);
                }
            bf16x8 pf[2][2];   // [kk2][hi/lo]
#pragma unroll
            for (int kk2 = 0; kk2 < 2; kk2++) {
                int off = (kk2 * 4 + quad) * 136 + l15 * 8;
                pf[kk2][0] = *(const bf16x8*)(Pw + off);
                pf[kk2][1] = *(const bf16x8*)(Pw + 1088 + off);
            }

            // ---- PV: out[q][d] += P·V ----
#pragma unroll
            for (int dc = 0; dc < 4; dc++) {
                f32x4 a = acc[nc][dc];
#pragma unroll
                for (int kk2 = 0; kk2 < 2; kk2++) {
                    a = __builtin_amdgcn_mfma_f32_16x16x32_bf16(pf[kk2][0], vf[dc][kk2][0], a, 0, 0, 0);
                    a = __builtin_amdgcn_mfma_f32_16x16x32_bf16(pf[kk2][1], vf[dc][kk2][0], a, 0, 0, 0);
                    a = __builtin_amdgcn_mfma_f32_16x16x32_bf16(pf[kk2][0], vf[dc][kk2][1], a, 0, 0, 0);
                }
                acc[nc][dc] = a;
            }
        }
    }

    // epilogue: divide by l, store fp32
#pragma unroll
    for (int nc = 0; nc < 2; nc++) {
        float linv = 1.f / lst[nc];
        float lr[4];
#pragma unroll
        for (int r = 0; r < 4; r++)
            lr[r] = __shfl(linv, (lane & 48) + ((lane >> 4) << 2) + r);
#pragma unroll
        for (int dc = 0; dc < 4; dc++)
#pragma unroll
            for (int r = 0; r < 4; r++) {
                int s = q_wave + nc * 16 + quad * 4 + r;
                out[((size_t)(b * SS + s)) * EE + h * HD + dc * 16 + l15] = acc[nc][dc][r] * lr[r];
            }
    }
}

extern "C" void kernel_launch(void* const* d_in, const int* in_sizes, int n_in,
                              void* d_out, int out_size, void* d_ws, size_t ws_size,
                              hipStream_t stream) {
    const float* X    = (const float*)d_in[0];
    const float* W    = (const float*)d_in[1];
    const float* bias = (const float*)d_in[2];
    float* out = (float*)d_out;

    float* ws = (float*)d_ws;
    float* ct = ws;                    // 65536 f32
    float* st = ws + 65536;            // 65536 f32
    unsigned short* base = (unsigned short*)(ws + 131072);
    const size_t ASZ = (size_t)32 * 131072;   // 4.19M bf16 per array
    unsigned short* Qh = base;
    unsigned short* Ql = base + ASZ;
    unsigned short* Kh = base + 2 * ASZ;
    unsigned short* Kl = base + 3 * ASZ;
    unsigned short* Vh = base + 4 * ASZ;
    unsigned short* Vl = base + 5 * ASZ;

    rope_table_k<<<(SS * HD2 + 255) / 256, 256, 0, stream>>>(ct, st);
    qkv_rope_k<<<dim3(3 * EE / 64, BB * SS / 64), 256, 0, stream>>>(
        X, W, bias, ct, st, Qh, Ql, Kh, Kl, Vh, Vl);
    attn_mfma_k<<<dim3(SS / 128, BB * NHH), 256, 0, stream>>>(
        Qh, Ql, Kh, Kl, Vh, Vl, out);
}

// Round 3
// 308.048 us; speedup vs baseline: 4.3546x; 2.3873x over previous
//
#include <hip/hip_runtime.h>
#include <math.h>

// Problem constants: B=2, S=2048, E=1024, NH=16, hd=64, T=1 (seq = S)
#define BB 2
#define SS 2048
#define EE 1024
#define NHH 16
#define HD 64
#define HD2 32

typedef __attribute__((ext_vector_type(8))) short bf16x8;   // 8 bf16 = 4 VGPRs
typedef __attribute__((ext_vector_type(8))) unsigned short ushort8_t;
typedef __attribute__((ext_vector_type(4))) float f32x4;    // MFMA accumulator

static __device__ __forceinline__ unsigned short f2bf(float x) {
    union { float f; unsigned u; } v; v.f = x;
    unsigned r = v.u + 0x7fffu + ((v.u >> 16) & 1u);   // round-to-nearest-even
    return (unsigned short)(r >> 16);
}
static __device__ __forceinline__ float bf2f(unsigned short h) {
    union { unsigned u; float f; } v; v.u = ((unsigned)h) << 16;
    return v.f;
}

// ---------------- kernel 1: RoPE cos/sin tables ----------------
__global__ __launch_bounds__(256) void rope_table_k(float* __restrict__ ct,
                                                    float* __restrict__ st) {
    int idx = blockIdx.x * 256 + threadIdx.x;   // idx = s*32 + p
    if (idx >= SS * HD2) return;
    int s = idx >> 5, p = idx & 31;
    double inv = pow(10000.0, -(double)(2 * p) / 64.0);
    double ang = (double)s * inv;
    ct[idx] = (float)cos(ang);
    st[idx] = (float)sin(ang);
}

// ---------------- kernel 2: QKV GEMM (split-bf16 MFMA) + bias + RoPE ------
// C = X @ W^T + bias. 128x128 tile, BK=32, 4 waves each 64x64 (4x4 of 16x16).
// Staging converts f32 -> bf16 hi/lo into swizzled LDS:
//   elem = (((grp*2+hl)*4+quad)*16 + l15)*8 + j   (grp = row/16, k = quad*8+j)
// Output layouts (per bh, 262144 bf16 elems, hi/lo interleaved at 256B):
//   Q/K: elem = ((((s>>4)*2 + (d>>5))*4 + ((d>>3)&3))*2 + hl)*128 + (s&15)*8 + (d&7)
//   V:   elem = ((((s>>5)*4 + (d>>4))*4 + ((s>>3)&3))*2 + hl)*128 + (d&15)*8 + (s&7)
__global__ __launch_bounds__(256, 2) void qkv_mfma_k(
    const float* __restrict__ X, const float* __restrict__ W,
    const float* __restrict__ bias,
    const float* __restrict__ ct, const float* __restrict__ st,
    unsigned short* __restrict__ Qg, unsigned short* __restrict__ Kg,
    unsigned short* __restrict__ Vg)
{
    __shared__ __align__(16) unsigned short Alds[8192];   // 16 KB
    __shared__ __align__(16) unsigned short Blds[8192];   // 16 KB

    const int tid  = threadIdx.x;
    const int wave = tid >> 6;
    const int lane = tid & 63;
    const int quad = lane >> 4;
    const int l15  = lane & 15;
    const int m0   = blockIdx.y * 128;
    const int n0b  = blockIdx.x * 128;

    // staging assignment: row r (0..127), k-segment ks (0 or 16)
    const int r  = tid >> 1;
    const int ks = (tid & 1) * 16;
    const int q0s = ks >> 3;            // first quad of this 16-elem segment
    const int grp_s = r >> 4;
    const int l15s  = r & 15;

    const float* ap = X + (size_t)(m0 + r) * EE + ks;
    const float* bp = W + (size_t)(n0b + r) * EE + ks;

    f32x4 acc[4][4];
#pragma unroll
    for (int mc = 0; mc < 4; mc++)
#pragma unroll
        for (int nc = 0; nc < 4; nc++) acc[mc][nc] = (f32x4){0.f, 0.f, 0.f, 0.f};

    // prefetch first tile
    float4 a[4], bb[4];
#pragma unroll
    for (int i = 0; i < 4; i++) {
        a[i]  = *(const float4*)(ap + i * 4);
        bb[i] = *(const float4*)(bp + i * 4);
    }

    const int mg = (wave >> 1) * 4;     // A group base for this wave
    const int ng = (wave & 1) * 4;      // B group base

    for (int kt = 0; kt < EE / 32; kt++) {
        __syncthreads();   // previous iteration's fragment reads done
        // ---- convert + write staged tile ----
#pragma unroll
        for (int half = 0; half < 2; half++) {
            int q = q0s + half;
            ushort8_t hi8a, lo8a, hi8b, lo8b;
#pragma unroll
            for (int j = 0; j < 8; j++) {
                float xa = ((const float*)&a[half * 2])[j];
                float xb = ((const float*)&bb[half * 2])[j];
                unsigned short ha = f2bf(xa);
                unsigned short hb = f2bf(xb);
                hi8a[j] = ha; lo8a[j] = f2bf(xa - bf2f(ha));
                hi8b[j] = hb; lo8b[j] = f2bf(xb - bf2f(hb));
            }
            int ehi = ((grp_s * 2 + 0) * 4 + q) * 128 + l15s * 8;
            int elo = ((grp_s * 2 + 1) * 4 + q) * 128 + l15s * 8;
            *(ushort8_t*)(Alds + ehi) = hi8a;
            *(ushort8_t*)(Alds + elo) = lo8a;
            *(ushort8_t*)(Blds + ehi) = hi8b;
            *(ushort8_t*)(Blds + elo) = lo8b;
        }
        __syncthreads();

        // ---- prefetch next tile (latency hidden by MFMA below) ----
        if (kt < EE / 32 - 1) {
            ap += 32; bp += 32;
#pragma unroll
            for (int i = 0; i < 4; i++) {
                a[i]  = *(const float4*)(ap + i * 4);
                bb[i] = *(const float4*)(bp + i * 4);
            }
        }

        // ---- fragments + MFMA ----
        bf16x8 Ah[4], Al[4], Bh[4], Bl[4];
#pragma unroll
        for (int mc = 0; mc < 4; mc++) {
            int base = ((mg + mc) * 8 + quad) * 128 + l15 * 8;
            Ah[mc] = *(const bf16x8*)(Alds + base);
            Al[mc] = *(const bf16x8*)(Alds + base + 512);
        }
#pragma unroll
        for (int nc = 0; nc < 4; nc++) {
            int base = ((ng + nc) * 8 + quad) * 128 + l15 * 8;
            Bh[nc] = *(const bf16x8*)(Blds + base);
            Bl[nc] = *(const bf16x8*)(Blds + base + 512);
        }
#pragma unroll
        for (int mc = 0; mc < 4; mc++)
#pragma unroll
            for (int nc = 0; nc < 4; nc++) {
                f32x4 c = acc[mc][nc];
                c = __builtin_amdgcn_mfma_f32_16x16x32_bf16(Ah[mc], Bh[nc], c, 0, 0, 0);
                c = __builtin_amdgcn_mfma_f32_16x16x32_bf16(Ah[mc], Bl[nc], c, 0, 0, 0);
                c = __builtin_amdgcn_mfma_f32_16x16x32_bf16(Al[mc], Bh[nc], c, 0, 0, 0);
                acc[mc][nc] = c;
            }
    }

    // ---- epilogue: bias + RoPE + hi/lo split + swizzled scatter ----
    const int n0w = n0b + (wave & 1) * 64;   // this wave's 64 cols (one head)
    const int m0w = m0 + (wave >> 1) * 64;   // this wave's 64 tokens (one batch)
    const int sec = n0w >> 10;               // 0=q,1=k,2=v (uniform per wave)
    const int h   = (n0w & 1023) >> 6;
    const int bq  = m0w >> 11;
    const size_t abase = (size_t)(bq * NHH + h) * 262144;
    unsigned short* dst = (sec == 0) ? Qg : (sec == 1) ? Kg : Vg;

    float bn[4];
#pragma unroll
    for (int nc = 0; nc < 4; nc++) bn[nc] = bias[n0w + nc * 16 + l15];

    if (sec < 2) {
        const float scq = (sec == 0) ? 0.125f : 1.0f;   // fold 1/sqrt(hd) into Q
#pragma unroll
        for (int mc = 0; mc < 4; mc++) {
            int sb = (m0w & 2047) + mc * 16;
#pragma unroll
            for (int nc = 0; nc < 4; nc++) {
                int d = nc * 16 + l15;
                int p = d >> 1;
                int kc = d >> 5, quad_a = (d >> 3) & 3, j = d & 7;
#pragma unroll
                for (int rr = 0; rr < 4; rr++) {
                    int srow = sb + quad * 4 + rr;
                    float x = acc[mc][nc][rr] + bn[nc];
                    float xp = __shfl_xor(x, 1);
                    float c = ct[srow * 32 + p], sn = st[srow * 32 + p];
                    float o = ((l15 & 1) == 0) ? (x * c - xp * sn) : (xp * sn + x * c);
                    o *= scq;
                    unsigned short hi = f2bf(o);
                    unsigned short lo = f2bf(o - bf2f(hi));
                    unsigned int packed = (unsigned)hi | ((unsigned)lo << 16);
                    unsigned int pp = (unsigned)__shfl_xor((int)packed, 1);
                    if ((l15 & 1) == 0) {
                        unsigned int hw = (packed & 0xffffu) | (pp << 16);
                        unsigned int lw = (packed >> 16) | (pp & 0xffff0000u);
                        size_t e = abase +
                            (size_t)((((srow >> 4) * 2 + kc) * 4 + quad_a) * 2) * 128 +
                            (srow & 15) * 8 + j;
                        *(unsigned int*)(dst + e)       = hw;
                        *(unsigned int*)(dst + e + 128) = lw;
                    }
                }
            }
        }
    } else {
#pragma unroll
        for (int mc = 0; mc < 4; mc++) {
            int sb = (m0w & 2047) + mc * 16;
            int s32 = sb >> 5;
            int quad_v = ((sb >> 3) + (quad >> 1)) & 3;
            int j0 = (quad & 1) * 4;
#pragma unroll
            for (int nc = 0; nc < 4; nc++) {
                unsigned short hv[4], lv[4];
#pragma unroll
                for (int rr = 0; rr < 4; rr++) {
                    float x = acc[mc][nc][rr] + bn[nc];
                    hv[rr] = f2bf(x);
                    lv[rr] = f2bf(x - bf2f(hv[rr]));
                }
                size_t e = abase +
                    (size_t)(((s32 * 4 + nc) * 4 + quad_v) * 2) * 128 + l15 * 8 + j0;
                *(ushort4*)(dst + e)       = make_ushort4(hv[0], hv[1], hv[2], hv[3]);
                *(ushort4*)(dst + e + 128) = make_ushort4(lv[0], lv[1], lv[2], lv[3]);
            }
        }
    }
}

// ---------------- kernel 3: flash attention, split-bf16 MFMA --------------
__global__ __launch_bounds__(256, 2) void attn_mfma_k(
    const unsigned short* __restrict__ Qg,
    const unsigned short* __restrict__ Kg,
    const unsigned short* __restrict__ Vg,
    float* __restrict__ out)
{
    __shared__ __align__(16) unsigned short Klds[8192];
    __shared__ __align__(16) unsigned short Vlds[8192];
    __shared__ __align__(16) unsigned short Pbuf[4][2176];  // per wave: hi [0,1088), lo [1088,2176)

    const int tid  = threadIdx.x;
    const int wave = tid >> 6;
    const int lane = tid & 63;
    const int quad = lane >> 4;
    const int l15  = lane & 15;
    const int bh   = blockIdx.y;
    const int b    = bh >> 4, h = bh & 15;
    const int q_wave = blockIdx.x * 128 + wave * 32;
    const size_t abase = (size_t)bh * 262144;

    // Q B-fragments (persistent): [nc][kc][hi/lo]
    bf16x8 qf[2][2][2];
#pragma unroll
    for (int nc = 0; nc < 2; nc++)
#pragma unroll
        for (int kc = 0; kc < 2; kc++) {
            size_t off = abase +
                (size_t)(((((q_wave >> 4) + nc) * 2 + kc) * 4 + quad) * 2) * 128 + l15 * 8;
            qf[nc][kc][0] = *(const bf16x8*)(Qg + off);
            qf[nc][kc][1] = *(const bf16x8*)(Qg + off + 128);
        }

    f32x4 acc[2][4];
#pragma unroll
    for (int nc = 0; nc < 2; nc++)
#pragma unroll
        for (int dc = 0; dc < 4; dc++) acc[nc][dc] = (f32x4){0.f, 0.f, 0.f, 0.f};
    float mst[2] = {-INFINITY, -INFINITY};
    float lst[2] = {0.f, 0.f};

    for (int kt = 0; kt < SS / 64; kt++) {
        __syncthreads();
        {
            const unsigned short* kg = Kg + abase + (size_t)kt * 8192;
            const unsigned short* vg = Vg + abase + (size_t)kt * 8192;
            float4 t0 = *(const float4*)(kg + tid * 8);
            float4 t1 = *(const float4*)(kg + (tid + 256) * 8);
            float4 t2 = *(const float4*)(kg + (tid + 512) * 8);
            float4 t3 = *(const float4*)(kg + (tid + 768) * 8);
            float4 t4 = *(const float4*)(vg + tid * 8);
            float4 t5 = *(const float4*)(vg + (tid + 256) * 8);
            float4 t6 = *(const float4*)(vg + (tid + 512) * 8);
            float4 t7 = *(const float4*)(vg + (tid + 768) * 8);
            *(float4*)(Klds + tid * 8)         = t0;
            *(float4*)(Klds + (tid + 256) * 8) = t1;
            *(float4*)(Klds + (tid + 512) * 8) = t2;
            *(float4*)(Klds + (tid + 768) * 8) = t3;
            *(float4*)(Vlds + tid * 8)         = t4;
            *(float4*)(Vlds + (tid + 256) * 8) = t5;
            *(float4*)(Vlds + (tid + 512) * 8) = t6;
            *(float4*)(Vlds + (tid + 768) * 8) = t7;
        }
        __syncthreads();

        // ---- QK^T (transposed: St[key][q]) ----
        f32x4 stt[2][4];   // [nc][mc]
#pragma unroll
        for (int mc = 0; mc < 4; mc++) {
            int off0 = ((mc * 2 + 0) * 4 + quad) * 256 + l15 * 8;
            int off1 = ((mc * 2 + 1) * 4 + quad) * 256 + l15 * 8;
            bf16x8 ah0 = *(const bf16x8*)(Klds + off0);
            bf16x8 ah1 = *(const bf16x8*)(Klds + off1);
            bf16x8 al0 = *(const bf16x8*)(Klds + off0 + 128);
            bf16x8 al1 = *(const bf16x8*)(Klds + off1 + 128);
#pragma unroll
            for (int nc = 0; nc < 2; nc++) {
                f32x4 s = (f32x4){0.f, 0.f, 0.f, 0.f};
                s = __builtin_amdgcn_mfma_f32_16x16x32_bf16(ah0, qf[nc][0][0], s, 0, 0, 0);
                s = __builtin_amdgcn_mfma_f32_16x16x32_bf16(ah1, qf[nc][1][0], s, 0, 0, 0);
                s = __builtin_amdgcn_mfma_f32_16x16x32_bf16(ah0, qf[nc][0][1], s, 0, 0, 0);
                s = __builtin_amdgcn_mfma_f32_16x16x32_bf16(ah1, qf[nc][1][1], s, 0, 0, 0);
                s = __builtin_amdgcn_mfma_f32_16x16x32_bf16(al0, qf[nc][0][0], s, 0, 0, 0);
                s = __builtin_amdgcn_mfma_f32_16x16x32_bf16(al1, qf[nc][1][0], s, 0, 0, 0);
                stt[nc][mc] = s;
            }
        }

        // ---- V B-fragments ----
        bf16x8 vf[4][2][2];   // [dc][kk2][hi/lo]
#pragma unroll
        for (int dc = 0; dc < 4; dc++)
#pragma unroll
            for (int kk2 = 0; kk2 < 2; kk2++) {
                int off = ((kk2 * 4 + dc) * 4 + quad) * 256 + l15 * 8;
                vf[dc][kk2][0] = *(const bf16x8*)(Vlds + off);
                vf[dc][kk2][1] = *(const bf16x8*)(Vlds + off + 128);
            }

#pragma unroll
        for (int nc = 0; nc < 2; nc++) {
            float mt = -INFINITY;
#pragma unroll
            for (int mc = 0; mc < 4; mc++)
#pragma unroll
                for (int rr = 0; rr < 4; rr++) mt = fmaxf(mt, stt[nc][mc][rr]);
            mt = fmaxf(mt, __shfl_xor(mt, 16));
            mt = fmaxf(mt, __shfl_xor(mt, 32));
            float mnew = fmaxf(mst[nc], mt);
            float alpha = __expf(mst[nc] - mnew);
            float p[4][4];
            float ps = 0.f;
#pragma unroll
            for (int mc = 0; mc < 4; mc++)
#pragma unroll
                for (int rr = 0; rr < 4; rr++) {
                    float e = __expf(stt[nc][mc][rr] - mnew);
                    p[mc][rr] = e;
                    ps += e;
                }
            ps += __shfl_xor(ps, 16);
            ps += __shfl_xor(ps, 32);
            lst[nc] = lst[nc] * alpha + ps;
            mst[nc] = mnew;

            float ar[4];
#pragma unroll
            for (int rr = 0; rr < 4; rr++)
                ar[rr] = __shfl(alpha, (lane & 48) + ((lane >> 4) << 2) + rr);
#pragma unroll
            for (int dc = 0; dc < 4; dc++)
#pragma unroll
                for (int rr = 0; rr < 4; rr++) acc[nc][dc][rr] *= ar[rr];

            // pack P hi/lo, LDS round-trip into A-operand layout
            unsigned short* Pw = Pbuf[wave];
#pragma unroll
            for (int mc = 0; mc < 4; mc++)
#pragma unroll
                for (int pr = 0; pr < 2; pr++) {
                    float p0f = p[mc][2 * pr], p1f = p[mc][2 * pr + 1];
                    unsigned short h0 = f2bf(p0f), h1 = f2bf(p1f);
                    unsigned short lo0 = f2bf(p0f - bf2f(h0));
                    unsigned short lo1 = f2bf(p1f - bf2f(h1));
                    int kk2 = mc >> 1;
                    int quadp = (mc & 1) * 2 + (quad >> 1);
                    int j = (quad & 1) * 4 + 2 * pr;
                    int off = (kk2 * 4 + quadp) * 136 + l15 * 8 + j;
                    *(unsigned int*)(Pw + off)        = (unsigned int)h0 | ((unsigned int)h1 << 16);
                    *(unsigned int*)(Pw + 1088 + off) = (unsigned int)lo0 | ((unsigned int)lo1 << 16);
                }
            bf16x8 pf[2][2];
#pragma unroll
            for (int kk2 = 0; kk2 < 2; kk2++) {
                int off = (kk2 * 4 + quad) * 136 + l15 * 8;
                pf[kk2][0] = *(const bf16x8*)(Pw + off);
                pf[kk2][1] = *(const bf16x8*)(Pw + 1088 + off);
            }

#pragma unroll
            for (int dc = 0; dc < 4; dc++) {
                f32x4 aa = acc[nc][dc];
#pragma unroll
                for (int kk2 = 0; kk2 < 2; kk2++) {
                    aa = __builtin_amdgcn_mfma_f32_16x16x32_bf16(pf[kk2][0], vf[dc][kk2][0], aa, 0, 0, 0);
                    aa = __builtin_amdgcn_mfma_f32_16x16x32_bf16(pf[kk2][1], vf[dc][kk2][0], aa, 0, 0, 0);
                    aa = __builtin_amdgcn_mfma_f32_16x16x32_bf16(pf[kk2][0], vf[dc][kk2][1], aa, 0, 0, 0);
                }
                acc[nc][dc] = aa;
            }
        }
    }

#pragma unroll
    for (int nc = 0; nc < 2; nc++) {
        float linv = 1.f / lst[nc];
        float lr[4];
#pragma unroll
        for (int rr = 0; rr < 4; rr++)
            lr[rr] = __shfl(linv, (lane & 48) + ((lane >> 4) << 2) + rr);
#pragma unroll
        for (int dc = 0; dc < 4; dc++)
#pragma unroll
            for (int rr = 0; rr < 4; rr++) {
                int s = q_wave + nc * 16 + quad * 4 + rr;
                out[((size_t)(b * SS + s)) * EE + h * HD + dc * 16 + l15] = acc[nc][dc][rr] * lr[rr];
            }
    }
}

extern "C" void kernel_launch(void* const* d_in, const int* in_sizes, int n_in,
                              void* d_out, int out_size, void* d_ws, size_t ws_size,
                              hipStream_t stream) {
    const float* X    = (const float*)d_in[0];
    const float* W    = (const float*)d_in[1];
    const float* bias = (const float*)d_in[2];
    float* out = (float*)d_out;

    float* ws = (float*)d_ws;
    float* ct = ws;                    // 65536 f32
    float* st = ws + 65536;            // 65536 f32
    unsigned short* base = (unsigned short*)(ws + 131072);
    const size_t ASZ = (size_t)32 * 262144;   // 8.39M bf16 per array (hi/lo interleaved)
    unsigned short* Qg = base;
    unsigned short* Kg = base + ASZ;
    unsigned short* Vg = base + 2 * ASZ;

    rope_table_k<<<(SS * HD2 + 255) / 256, 256, 0, stream>>>(ct, st);
    qkv_mfma_k<<<dim3(3 * EE / 128, BB * SS / 128), 256, 0, stream>>>(
        X, W, bias, ct, st, Qg, Kg, Vg);
    attn_mfma_k<<<dim3(SS / 128, BB * NHH), 256, 0, stream>>>(Qg, Kg, Vg, out);
}

// Round 4
// 284.145 us; speedup vs baseline: 4.7209x; 1.0841x over previous
//
#include <hip/hip_runtime.h>
#include <math.h>

// Problem constants: B=2, S=2048, E=1024, NH=16, hd=64, T=1 (seq = S)
#define BB 2
#define SS 2048
#define EE 1024
#define NHH 16
#define HD 64
#define HD2 32

typedef __attribute__((ext_vector_type(8))) short bf16x8;   // 8 bf16 = 4 VGPRs
typedef __attribute__((ext_vector_type(4))) float f32x4;    // MFMA accumulator

// ---- cheap split-bf16 helpers (RTZ hi + RTZ lo residual; hi+lo ~ 2^-16 rel) ----
// pk_hi(a,b): packs bf16_rtz(a) into low16, bf16_rtz(b) into high16 — 1 v_perm_b32.
static __device__ __forceinline__ unsigned pk_hi(float a, float b) {
    union { float f; unsigned u; } x, y; x.f = a; y.f = b;
    return __builtin_amdgcn_perm(y.u, x.u, 0x07060302u);
}
static __device__ __forceinline__ float hi_trunc(float a) {
    union { float f; unsigned u; } x; x.f = a; x.u &= 0xffff0000u;
    return x.f;
}
// packed = hi | lo<<16 for one value (epilogue format)
static __device__ __forceinline__ unsigned split_pack(float o) {
    return pk_hi(o, o - hi_trunc(o));
}

// ---------------- kernel 1: RoPE cos/sin tables ----------------
__global__ __launch_bounds__(256) void rope_table_k(float* __restrict__ ct,
                                                    float* __restrict__ st) {
    int idx = blockIdx.x * 256 + threadIdx.x;   // idx = s*32 + p
    if (idx >= SS * HD2) return;
    int s = idx >> 5, p = idx & 31;
    double inv = pow(10000.0, -(double)(2 * p) / 64.0);
    double ang = (double)s * inv;
    ct[idx] = (float)cos(ang);
    st[idx] = (float)sin(ang);
}

// ---------------- kernel 2: QKV GEMM (split-bf16 MFMA) + bias + RoPE ------
// C = X @ W^T + bias. 128x128 tile, BK=32, 4 waves each 64x64 (4x4 of 16x16).
// Q is pre-scaled by 0.125*log2(e) so attention can use exp2 directly.
__global__ __launch_bounds__(256, 2) void qkv_mfma_k(
    const float* __restrict__ X, const float* __restrict__ W,
    const float* __restrict__ bias,
    const float* __restrict__ ct, const float* __restrict__ st,
    unsigned short* __restrict__ Qg, unsigned short* __restrict__ Kg,
    unsigned short* __restrict__ Vg)
{
    __shared__ __align__(16) unsigned short Alds[8192];   // 16 KB
    __shared__ __align__(16) unsigned short Blds[8192];   // 16 KB

    const int tid  = threadIdx.x;
    const int wave = tid >> 6;
    const int lane = tid & 63;
    const int quad = lane >> 4;
    const int l15  = lane & 15;
    const int m0   = blockIdx.y * 128;
    const int n0b  = blockIdx.x * 128;

    const int r  = tid >> 1;
    const int ks = (tid & 1) * 16;
    const int q0s = ks >> 3;
    const int grp_s = r >> 4;
    const int l15s  = r & 15;

    const float* ap = X + (size_t)(m0 + r) * EE + ks;
    const float* bp = W + (size_t)(n0b + r) * EE + ks;

    f32x4 acc[4][4];
#pragma unroll
    for (int mc = 0; mc < 4; mc++)
#pragma unroll
        for (int nc = 0; nc < 4; nc++) acc[mc][nc] = (f32x4){0.f, 0.f, 0.f, 0.f};

    float4 a[4], bb[4];
#pragma unroll
    for (int i = 0; i < 4; i++) {
        a[i]  = *(const float4*)(ap + i * 4);
        bb[i] = *(const float4*)(bp + i * 4);
    }

    const int mg = (wave >> 1) * 4;
    const int ng = (wave & 1) * 4;

    for (int kt = 0; kt < EE / 32; kt++) {
        __syncthreads();
        // ---- convert (RTZ hi/lo, perm-packed) + write staged tile ----
#pragma unroll
        for (int half = 0; half < 2; half++) {
            int q = q0s + half;
            const float* fa = (const float*)&a[half * 2];
            const float* fb = (const float*)&bb[half * 2];
            unsigned hia[4], loa[4], hib[4], lob[4];
#pragma unroll
            for (int jj = 0; jj < 4; jj++) {
                float pa0 = fa[2 * jj], pa1 = fa[2 * jj + 1];
                hia[jj] = pk_hi(pa0, pa1);
                loa[jj] = pk_hi(pa0 - hi_trunc(pa0), pa1 - hi_trunc(pa1));
                float pb0 = fb[2 * jj], pb1 = fb[2 * jj + 1];
                hib[jj] = pk_hi(pb0, pb1);
                lob[jj] = pk_hi(pb0 - hi_trunc(pb0), pb1 - hi_trunc(pb1));
            }
            int ehi = ((grp_s * 2 + 0) * 4 + q) * 128 + l15s * 8;
            int elo = ((grp_s * 2 + 1) * 4 + q) * 128 + l15s * 8;
            *(uint4*)(Alds + ehi) = make_uint4(hia[0], hia[1], hia[2], hia[3]);
            *(uint4*)(Alds + elo) = make_uint4(loa[0], loa[1], loa[2], loa[3]);
            *(uint4*)(Blds + ehi) = make_uint4(hib[0], hib[1], hib[2], hib[3]);
            *(uint4*)(Blds + elo) = make_uint4(lob[0], lob[1], lob[2], lob[3]);
        }
        __syncthreads();

        if (kt < EE / 32 - 1) {
            ap += 32; bp += 32;
#pragma unroll
            for (int i = 0; i < 4; i++) {
                a[i]  = *(const float4*)(ap + i * 4);
                bb[i] = *(const float4*)(bp + i * 4);
            }
        }

        bf16x8 Ah[4], Al[4], Bh[4], Bl[4];
#pragma unroll
        for (int mc = 0; mc < 4; mc++) {
            int base = ((mg + mc) * 8 + quad) * 128 + l15 * 8;
            Ah[mc] = *(const bf16x8*)(Alds + base);
            Al[mc] = *(const bf16x8*)(Alds + base + 512);
        }
#pragma unroll
        for (int nc = 0; nc < 4; nc++) {
            int base = ((ng + nc) * 8 + quad) * 128 + l15 * 8;
            Bh[nc] = *(const bf16x8*)(Blds + base);
            Bl[nc] = *(const bf16x8*)(Blds + base + 512);
        }
#pragma unroll
        for (int mc = 0; mc < 4; mc++)
#pragma unroll
            for (int nc = 0; nc < 4; nc++) {
                f32x4 c = acc[mc][nc];
                c = __builtin_amdgcn_mfma_f32_16x16x32_bf16(Ah[mc], Bh[nc], c, 0, 0, 0);
                c = __builtin_amdgcn_mfma_f32_16x16x32_bf16(Ah[mc], Bl[nc], c, 0, 0, 0);
                c = __builtin_amdgcn_mfma_f32_16x16x32_bf16(Al[mc], Bh[nc], c, 0, 0, 0);
                acc[mc][nc] = c;
            }
    }

    // ---- epilogue: bias + RoPE + hi/lo split + swizzled scatter ----
    const int n0w = n0b + (wave & 1) * 64;
    const int m0w = m0 + (wave >> 1) * 64;
    const int sec = n0w >> 10;
    const int h   = (n0w & 1023) >> 6;
    const int bq  = m0w >> 11;
    const size_t abase = (size_t)(bq * NHH + h) * 262144;
    unsigned short* dst = (sec == 0) ? Qg : (sec == 1) ? Kg : Vg;

    float bn[4];
#pragma unroll
    for (int nc = 0; nc < 4; nc++) bn[nc] = bias[n0w + nc * 16 + l15];

    if (sec < 2) {
        // Q gets 0.125 * log2(e) so attention softmax can use exp2 directly
        const float scq = (sec == 0) ? 0.18033688f : 1.0f;
#pragma unroll
        for (int mc = 0; mc < 4; mc++) {
            int sb = (m0w & 2047) + mc * 16;
#pragma unroll
            for (int nc = 0; nc < 4; nc++) {
                int d = nc * 16 + l15;
                int p = d >> 1;
                int kc = d >> 5, quad_a = (d >> 3) & 3, j = d & 7;
#pragma unroll
                for (int rr = 0; rr < 4; rr++) {
                    int srow = sb + quad * 4 + rr;
                    float x = acc[mc][nc][rr] + bn[nc];
                    float xp = __shfl_xor(x, 1);
                    float c = ct[srow * 32 + p], sn = st[srow * 32 + p];
                    float o = ((l15 & 1) == 0) ? (x * c - xp * sn) : (xp * sn + x * c);
                    o *= scq;
                    unsigned int packed = split_pack(o);   // hi | lo<<16
                    unsigned int pp = (unsigned)__shfl_xor((int)packed, 1);
                    if ((l15 & 1) == 0) {
                        unsigned int hw = (packed & 0xffffu) | (pp << 16);
                        unsigned int lw = (packed >> 16) | (pp & 0xffff0000u);
                        size_t e = abase +
                            (size_t)((((srow >> 4) * 2 + kc) * 4 + quad_a) * 2) * 128 +
                            (srow & 15) * 8 + j;
                        *(unsigned int*)(dst + e)       = hw;
                        *(unsigned int*)(dst + e + 128) = lw;
                    }
                }
            }
        }
    } else {
#pragma unroll
        for (int mc = 0; mc < 4; mc++) {
            int sb = (m0w & 2047) + mc * 16;
            int s32 = sb >> 5;
            int quad_v = ((sb >> 3) + (quad >> 1)) & 3;
            int j0 = (quad & 1) * 4;
#pragma unroll
            for (int nc = 0; nc < 4; nc++) {
                float x0 = acc[mc][nc][0] + bn[nc];
                float x1 = acc[mc][nc][1] + bn[nc];
                float x2 = acc[mc][nc][2] + bn[nc];
                float x3 = acc[mc][nc][3] + bn[nc];
                unsigned h01 = pk_hi(x0, x1), h23 = pk_hi(x2, x3);
                unsigned l01 = pk_hi(x0 - hi_trunc(x0), x1 - hi_trunc(x1));
                unsigned l23 = pk_hi(x2 - hi_trunc(x2), x3 - hi_trunc(x3));
                size_t e = abase +
                    (size_t)(((s32 * 4 + nc) * 4 + quad_v) * 2) * 128 + l15 * 8 + j0;
                *(uint2*)(dst + e)       = make_uint2(h01, h23);
                *(uint2*)(dst + e + 128) = make_uint2(l01, l23);
            }
        }
    }
}

// ---------------- kernel 3: flash attention, split-bf16 MFMA --------------
__global__ __launch_bounds__(256, 2) void attn_mfma_k(
    const unsigned short* __restrict__ Qg,
    const unsigned short* __restrict__ Kg,
    const unsigned short* __restrict__ Vg,
    float* __restrict__ out)
{
    __shared__ __align__(16) unsigned short Klds[8192];
    __shared__ __align__(16) unsigned short Vlds[8192];
    __shared__ __align__(16) unsigned short Pbuf[4][2176];

    const int tid  = threadIdx.x;
    const int wave = tid >> 6;
    const int lane = tid & 63;
    const int quad = lane >> 4;
    const int l15  = lane & 15;
    const int bh   = blockIdx.y;
    const int b    = bh >> 4, h = bh & 15;
    const int q_wave = blockIdx.x * 128 + wave * 32;
    const size_t abase = (size_t)bh * 262144;

    bf16x8 qf[2][2][2];
#pragma unroll
    for (int nc = 0; nc < 2; nc++)
#pragma unroll
        for (int kc = 0; kc < 2; kc++) {
            size_t off = abase +
                (size_t)(((((q_wave >> 4) + nc) * 2 + kc) * 4 + quad) * 2) * 128 + l15 * 8;
            qf[nc][kc][0] = *(const bf16x8*)(Qg + off);
            qf[nc][kc][1] = *(const bf16x8*)(Qg + off + 128);
        }

    f32x4 acc[2][4];
#pragma unroll
    for (int nc = 0; nc < 2; nc++)
#pragma unroll
        for (int dc = 0; dc < 4; dc++) acc[nc][dc] = (f32x4){0.f, 0.f, 0.f, 0.f};
    float mst[2] = {-INFINITY, -INFINITY};
    float lst[2] = {0.f, 0.f};

    for (int kt = 0; kt < SS / 64; kt++) {
        __syncthreads();
        {
            const unsigned short* kg = Kg + abase + (size_t)kt * 8192;
            const unsigned short* vg = Vg + abase + (size_t)kt * 8192;
            float4 t0 = *(const float4*)(kg + tid * 8);
            float4 t1 = *(const float4*)(kg + (tid + 256) * 8);
            float4 t2 = *(const float4*)(kg + (tid + 512) * 8);
            float4 t3 = *(const float4*)(kg + (tid + 768) * 8);
            float4 t4 = *(const float4*)(vg + tid * 8);
            float4 t5 = *(const float4*)(vg + (tid + 256) * 8);
            float4 t6 = *(const float4*)(vg + (tid + 512) * 8);
            float4 t7 = *(const float4*)(vg + (tid + 768) * 8);
            *(float4*)(Klds + tid * 8)         = t0;
            *(float4*)(Klds + (tid + 256) * 8) = t1;
            *(float4*)(Klds + (tid + 512) * 8) = t2;
            *(float4*)(Klds + (tid + 768) * 8) = t3;
            *(float4*)(Vlds + tid * 8)         = t4;
            *(float4*)(Vlds + (tid + 256) * 8) = t5;
            *(float4*)(Vlds + (tid + 512) * 8) = t6;
            *(float4*)(Vlds + (tid + 768) * 8) = t7;
        }
        __syncthreads();

        // ---- QK^T (transposed: St[key][q]), scores already in log2 domain ----
        f32x4 stt[2][4];
#pragma unroll
        for (int mc = 0; mc < 4; mc++) {
            int off0 = ((mc * 2 + 0) * 4 + quad) * 256 + l15 * 8;
            int off1 = ((mc * 2 + 1) * 4 + quad) * 256 + l15 * 8;
            bf16x8 ah0 = *(const bf16x8*)(Klds + off0);
            bf16x8 ah1 = *(const bf16x8*)(Klds + off1);
            bf16x8 al0 = *(const bf16x8*)(Klds + off0 + 128);
            bf16x8 al1 = *(const bf16x8*)(Klds + off1 + 128);
#pragma unroll
            for (int nc = 0; nc < 2; nc++) {
                f32x4 s = (f32x4){0.f, 0.f, 0.f, 0.f};
                s = __builtin_amdgcn_mfma_f32_16x16x32_bf16(ah0, qf[nc][0][0], s, 0, 0, 0);
                s = __builtin_amdgcn_mfma_f32_16x16x32_bf16(ah1, qf[nc][1][0], s, 0, 0, 0);
                s = __builtin_amdgcn_mfma_f32_16x16x32_bf16(ah0, qf[nc][0][1], s, 0, 0, 0);
                s = __builtin_amdgcn_mfma_f32_16x16x32_bf16(ah1, qf[nc][1][1], s, 0, 0, 0);
                s = __builtin_amdgcn_mfma_f32_16x16x32_bf16(al0, qf[nc][0][0], s, 0, 0, 0);
                s = __builtin_amdgcn_mfma_f32_16x16x32_bf16(al1, qf[nc][1][0], s, 0, 0, 0);
                stt[nc][mc] = s;
            }
        }

        bf16x8 vf[4][2][2];
#pragma unroll
        for (int dc = 0; dc < 4; dc++)
#pragma unroll
            for (int kk2 = 0; kk2 < 2; kk2++) {
                int off = ((kk2 * 4 + dc) * 4 + quad) * 256 + l15 * 8;
                vf[dc][kk2][0] = *(const bf16x8*)(Vlds + off);
                vf[dc][kk2][1] = *(const bf16x8*)(Vlds + off + 128);
            }

#pragma unroll
        for (int nc = 0; nc < 2; nc++) {
            float mt = -INFINITY;
#pragma unroll
            for (int mc = 0; mc < 4; mc++)
#pragma unroll
                for (int rr = 0; rr < 4; rr++) mt = fmaxf(mt, stt[nc][mc][rr]);
            mt = fmaxf(mt, __shfl_xor(mt, 16));
            mt = fmaxf(mt, __shfl_xor(mt, 32));
            float mnew = fmaxf(mst[nc], mt);
            float alpha = __builtin_amdgcn_exp2f(mst[nc] - mnew);
            float p[4][4];
            float ps = 0.f;
#pragma unroll
            for (int mc = 0; mc < 4; mc++)
#pragma unroll
                for (int rr = 0; rr < 4; rr++) {
                    float e = __builtin_amdgcn_exp2f(stt[nc][mc][rr] - mnew);
                    p[mc][rr] = e;
                    ps += e;
                }
            ps += __shfl_xor(ps, 16);
            ps += __shfl_xor(ps, 32);
            lst[nc] = lst[nc] * alpha + ps;
            mst[nc] = mnew;

            float ar[4];
#pragma unroll
            for (int rr = 0; rr < 4; rr++)
                ar[rr] = __shfl(alpha, (lane & 48) + ((lane >> 4) << 2) + rr);
#pragma unroll
            for (int dc = 0; dc < 4; dc++)
#pragma unroll
                for (int rr = 0; rr < 4; rr++) acc[nc][dc][rr] *= ar[rr];

            // pack P hi/lo (perm-packed RTZ), LDS round-trip into A-operand layout
            unsigned short* Pw = Pbuf[wave];
#pragma unroll
            for (int mc = 0; mc < 4; mc++)
#pragma unroll
                for (int pr = 0; pr < 2; pr++) {
                    float p0f = p[mc][2 * pr], p1f = p[mc][2 * pr + 1];
                    unsigned hw = pk_hi(p0f, p1f);
                    unsigned lw = pk_hi(p0f - hi_trunc(p0f), p1f - hi_trunc(p1f));
                    int kk2 = mc >> 1;
                    int quadp = (mc & 1) * 2 + (quad >> 1);
                    int j = (quad & 1) * 4 + 2 * pr;
                    int off = (kk2 * 4 + quadp) * 136 + l15 * 8 + j;
                    *(unsigned int*)(Pw + off)        = hw;
                    *(unsigned int*)(Pw + 1088 + off) = lw;
                }
            bf16x8 pf[2][2];
#pragma unroll
            for (int kk2 = 0; kk2 < 2; kk2++) {
                int off = (kk2 * 4 + quad) * 136 + l15 * 8;
                pf[kk2][0] = *(const bf16x8*)(Pw + off);
                pf[kk2][1] = *(const bf16x8*)(Pw + 1088 + off);
            }

#pragma unroll
            for (int dc = 0; dc < 4; dc++) {
                f32x4 aa = acc[nc][dc];
#pragma unroll
                for (int kk2 = 0; kk2 < 2; kk2++) {
                    aa = __builtin_amdgcn_mfma_f32_16x16x32_bf16(pf[kk2][0], vf[dc][kk2][0], aa, 0, 0, 0);
                    aa = __builtin_amdgcn_mfma_f32_16x16x32_bf16(pf[kk2][1], vf[dc][kk2][0], aa, 0, 0, 0);
                    aa = __builtin_amdgcn_mfma_f32_16x16x32_bf16(pf[kk2][0], vf[dc][kk2][1], aa, 0, 0, 0);
                }
                acc[nc][dc] = aa;
            }
        }
    }

#pragma unroll
    for (int nc = 0; nc < 2; nc++) {
        float linv = 1.f / lst[nc];
        float lr[4];
#pragma unroll
        for (int rr = 0; rr < 4; rr++)
            lr[rr] = __shfl(linv, (lane & 48) + ((lane >> 4) << 2) + rr);
#pragma unroll
        for (int dc = 0; dc < 4; dc++)
#pragma unroll
            for (int rr = 0; rr < 4; rr++) {
                int s = q_wave + nc * 16 + quad * 4 + rr;
                out[((size_t)(b * SS + s)) * EE + h * HD + dc * 16 + l15] = acc[nc][dc][rr] * lr[rr];
            }
    }
}

extern "C" void kernel_launch(void* const* d_in, const int* in_sizes, int n_in,
                              void* d_out, int out_size, void* d_ws, size_t ws_size,
                              hipStream_t stream) {
    const float* X    = (const float*)d_in[0];
    const float* W    = (const float*)d_in[1];
    const float* bias = (const float*)d_in[2];
    float* out = (float*)d_out;

    float* ws = (float*)d_ws;
    float* ct = ws;                    // 65536 f32
    float* st = ws + 65536;            // 65536 f32
    unsigned short* base = (unsigned short*)(ws + 131072);
    const size_t ASZ = (size_t)32 * 262144;   // 8.39M bf16 per array (hi/lo interleaved)
    unsigned short* Qg = base;
    unsigned short* Kg = base + ASZ;
    unsigned short* Vg = base + 2 * ASZ;

    rope_table_k<<<(SS * HD2 + 255) / 256, 256, 0, stream>>>(ct, st);
    qkv_mfma_k<<<dim3(3 * EE / 128, BB * SS / 128), 256, 0, stream>>>(
        X, W, bias, ct, st, Qg, Kg, Vg);
    attn_mfma_k<<<dim3(SS / 128, BB * NHH), 256, 0, stream>>>(Qg, Kg, Vg, out);
}